// Round 10
// baseline (145.267 us; speedup 1.0000x reference)
//
#include <hip/hip_runtime.h>

#define D_MODEL 512
#define DFF 2048
#define NEXP 8
#define LTOK 4096          // B*N tokens
#define NPAIR 8192         // LTOK * K
#define PMAX 9216          // padded gathered rows (8192 + 8*128)
#define MAXT 72            // max 128-row M-tiles

// hdr (int) offsets within ws
#define HD_COUNTS 0
#define HD_CURSOR 8
#define HD_OFF    16
#define HD_NTILES 25
#define HD_TILE_E 32
#define HD_TILE_R 112

typedef __attribute__((ext_vector_type(8))) short bf16x8;
typedef __attribute__((ext_vector_type(4))) float f32x4;

__device__ __forceinline__ unsigned short f2bf(float f){
  unsigned u = __builtin_bit_cast(unsigned, f);
  u += 0x7fffu + ((u>>16)&1u);        // RNE round to bf16
  return (unsigned short)(u>>16);
}

template<int N> __device__ __forceinline__ void wait_vm(){
  if constexpr (N==8)      asm volatile("s_waitcnt vmcnt(8)" ::: "memory");
  else if constexpr (N==6) asm volatile("s_waitcnt vmcnt(6)" ::: "memory");
  else if constexpr (N==4) asm volatile("s_waitcnt vmcnt(4)" ::: "memory");
  else if constexpr (N==3) asm volatile("s_waitcnt vmcnt(3)" ::: "memory");
  else                     asm volatile("s_waitcnt vmcnt(0)" ::: "memory");
}
#define RAW_BARRIER() asm volatile("s_barrier" ::: "memory")

// ---------------- router: fp64 logits, top-2, weights (NO atomics) ----------------
__global__ void router_top2(const float* __restrict__ x, const float* __restrict__ rw,
                            int* __restrict__ pair_e, float* __restrict__ pair_w){
  int t = blockIdx.x;
  int l = threadIdx.x;
  const float* xr = x + (size_t)t*D_MODEL;
  float xv[8];
  #pragma unroll
  for (int j=0;j<8;j++) xv[j] = xr[j*64+l];
  double lg[NEXP];
  #pragma unroll
  for (int e=0;e<NEXP;e++){
    const float* we = rw + e*D_MODEL;
    double s = 0.0;
    #pragma unroll
    for (int j=0;j<8;j++) s += (double)xv[j] * (double)we[j*64+l];
    #pragma unroll
    for (int off=32; off; off>>=1) s += __shfl_xor(s, off);
    lg[e] = s;
  }
  if (l==0){
    double mx = lg[0];
    #pragma unroll
    for (int e=1;e<NEXP;e++) if (lg[e]>mx) mx = lg[e];
    double p[NEXP], sum = 0.0;
    #pragma unroll
    for (int e=0;e<NEXP;e++){ p[e] = exp(lg[e]-mx); sum += p[e]; }
    #pragma unroll
    for (int e=0;e<NEXP;e++) p[e] /= sum;
    int i0 = 0;
    for (int e=1;e<NEXP;e++) if (p[e] > p[i0]) i0 = e;        // ties -> lower idx
    int i1 = (i0==0) ? 1 : 0;
    for (int e=0;e<NEXP;e++){ if (e==i0) continue; if (p[e] > p[i1]) i1 = e; }
    double s2 = p[i0] + p[i1] + 1e-9;
    pair_e[2*t]   = i0;  pair_e[2*t+1] = i1;
    pair_w[2*t]   = (float)(p[i0]/s2);
    pair_w[2*t+1] = (float)(p[i1]/s2);
  }
}

// ---------------- convert w1,w2 fp32 -> bf16 ----------------
__global__ void convw_kernel(const float* __restrict__ w1, const float* __restrict__ w2,
                             unsigned short* __restrict__ w1b, unsigned short* __restrict__ w2b){
  int id = blockIdx.x*256 + threadIdx.x;     // one per 8 elements
  const int per = NEXP*DFF*D_MODEL/8;        // 1048576
  const float* src; unsigned short* dst; int k;
  if (id < per){ src = w1; dst = w1b; k = id; }
  else         { src = w2; dst = w2b; k = id - per; }
  const float4* s = (const float4*)(src + (size_t)k*8);
  float4 a = s[0], b = s[1];
  uint4 o;
  o.x = (unsigned)f2bf(a.x) | ((unsigned)f2bf(a.y)<<16);
  o.y = (unsigned)f2bf(a.z) | ((unsigned)f2bf(a.w)<<16);
  o.z = (unsigned)f2bf(b.x) | ((unsigned)f2bf(b.y)<<16);
  o.w = (unsigned)f2bf(b.z) | ((unsigned)f2bf(b.w)<<16);
  *(uint4*)(dst + (size_t)k*8) = o;
}

// ---------------- count: LDS histogram, 8 global atomics per block ----------------
__global__ void count_kernel(const int* __restrict__ pair_e, int* __restrict__ hdr){
  __shared__ int cnt[NEXP];
  int tid = threadIdx.x;
  if (tid < NEXP) cnt[tid] = 0;
  __syncthreads();
  int base = blockIdx.x*1024;
  #pragma unroll
  for (int i=0;i<4;i++) atomicAdd(&cnt[pair_e[base + i*256 + tid]], 1);
  __syncthreads();
  if (tid < NEXP) atomicAdd(&hdr[HD_COUNTS+tid], cnt[tid]);
}

// ---------------- plan: padded offsets + tile table + gtk defaults ----------------
__global__ void plan_kernel(int* __restrict__ hdr, int* __restrict__ gtk){
  if (threadIdx.x==0){
    int off=0, nt=0;
    for (int e=0;e<NEXP;e++){
      hdr[HD_OFF+e]=off;
      int c = hdr[HD_COUNTS+e];
      int tiles = (c+127)>>7;
      for (int i=0;i<tiles;i++){ hdr[HD_TILE_E+nt]=e; hdr[HD_TILE_R+nt]=off+(i<<7); nt++; }
      off += tiles<<7;
    }
    hdr[HD_OFF+NEXP]=off;
    hdr[HD_NTILES]=nt;
  }
  for (int i=threadIdx.x; i<PMAX; i+=blockDim.x) gtk[i]=-1;
}

// -------- assign + gather: LDS rank, range reservation, then copy x rows --------
__global__ void assign_gather_kernel(const int* __restrict__ pair_e, int* __restrict__ hdr,
                                     int* __restrict__ gtk, int* __restrict__ pr,
                                     const float* __restrict__ x,
                                     unsigned short* __restrict__ xg){
  __shared__ int cnt[NEXP];
  __shared__ int base[NEXP];
  __shared__ int rowbuf[256];
  int tid = threadIdx.x;
  if (tid < NEXP) cnt[tid] = 0;
  __syncthreads();
  int id = blockIdx.x*256 + tid;
  int e = pair_e[id];
  int myrank = atomicAdd(&cnt[e], 1);           // LDS atomic
  __syncthreads();
  if (tid < NEXP) base[tid] = atomicAdd(&hdr[HD_CURSOR+tid], cnt[tid]);  // 8 global/block
  __syncthreads();
  int row = hdr[HD_OFF+e] + base[e] + myrank;
  gtk[row] = id;
  pr[id]   = row;
  rowbuf[tid] = row;
  __syncthreads();
  int grp = tid>>6, sub = tid&63;
  int base0 = blockIdx.x*256;
  for (int p = grp; p < 256; p += 4){
    int r = rowbuf[p];
    int t = (base0 + p)>>1;
    const float4* s = (const float4*)(x + (size_t)t*D_MODEL + sub*8);
    float4 a = s[0], b = s[1];
    uint4 o;
    o.x = (unsigned)f2bf(a.x) | ((unsigned)f2bf(a.y)<<16);
    o.y = (unsigned)f2bf(a.z) | ((unsigned)f2bf(a.w)<<16);
    o.z = (unsigned)f2bf(b.x) | ((unsigned)f2bf(b.y)<<16);
    o.w = (unsigned)f2bf(b.z) | ((unsigned)f2bf(b.w)<<16);
    *(uint4*)(xg + (size_t)r*D_MODEL + sub*8) = o;
  }
}

// ---- GEMM1: 128x128 tile, BK=32, 4 waves 2x2 of 64x64, 32KB LDS -> 5 blk/CU ----
// A=xg [PMAX][512] bf16; B=w1b [NEXP][2048][512] bf16 (B^T).
// 64B rows: swizzle ch ^= (r>>1)&3 (write+read) -> 2-way banks (free).
// h = relu(acc+bias) bf16.
__global__ __launch_bounds__(256,4) void gemm1_k(
    const unsigned short* __restrict__ A,
    const unsigned short* __restrict__ Bw,
    const float* __restrict__ bias,
    unsigned short* __restrict__ outH,
    const int* __restrict__ hdr)
{
  constexpr int NWG = MAXT*16;                 // 1152
  constexpr int NTK = D_MODEL/32;              // 16
  __shared__ __align__(16) unsigned short As[2*128*32];   // 16KB
  __shared__ __align__(16) unsigned short Bs[2*128*32];   // 16KB

  int wg  = blockIdx.x;
  int swz = (wg & 7)*(NWG/8) + (wg >> 3);
  int m   = swz >> 4;
  int n0  = (swz & 15) << 7;

  if (m >= hdr[HD_NTILES]) return;
  int e    = hdr[HD_TILE_E+m];
  int row0 = hdr[HD_TILE_R+m];

  int tid = threadIdx.x;
  int w = tid>>6, l = tid&63;
  int wm = w>>1, wn = w&1;

  const unsigned short* Ag = A  + (size_t)row0*D_MODEL;
  const unsigned short* Bg = Bw + (size_t)e*DFF*D_MODEL + (size_t)n0*D_MODEL;

  f32x4 acc[4][4];
  f32x4 zz = {0.f,0.f,0.f,0.f};
  #pragma unroll
  for (int i=0;i<4;i++)
    #pragma unroll
    for (int j=0;j<4;j++) acc[i][j] = zz;

  int srow = tid>>2;              // 0..63 rows per 4KB issue
  int c4   = tid&3;               // physical 16B chunk within 64B row
  char* AsB = (char*)As;
  char* BsB = (char*)Bs;

  auto stage = [&](int b, int kt){
    #pragma unroll
    for (int i=0;i<2;i++){
      int r  = i*64 + srow;
      int sc = (c4 ^ ((r>>1)&3))*8;                  // inverse-swizzled source (elems)
      const unsigned short* ga = Ag + (size_t)r*D_MODEL + kt*32 + sc;
      int ldso = b*8192 + i*4096 + tid*16;           // linear LDS dest (bytes)
      __builtin_amdgcn_global_load_lds((const __attribute__((address_space(1))) void*)ga,
                                       (__attribute__((address_space(3))) void*)(AsB + ldso), 16, 0, 0);
    }
    #pragma unroll
    for (int i=0;i<2;i++){
      int r  = i*64 + srow;
      int sc = (c4 ^ ((r>>1)&3))*8;
      const unsigned short* gb = Bg + (size_t)r*D_MODEL + kt*32 + sc;
      int ldso = b*8192 + i*4096 + tid*16;
      __builtin_amdgcn_global_load_lds((const __attribute__((address_space(1))) void*)gb,
                                       (__attribute__((address_space(3))) void*)(BsB + ldso), 16, 0, 0);
    }
  };

  auto compute = [&](int b){
    bf16x8 av[4], bv[4];
    #pragma unroll
    for (int mi=0;mi<4;mi++){
      int r  = (wm<<6) + (mi<<4) + (l&15);
      int ch = (l>>4) ^ ((r>>1)&3);                  // swizzled read chunk
      av[mi] = *(const bf16x8*)(AsB + b*8192 + r*64 + ch*16);
    }
    #pragma unroll
    for (int ni=0;ni<4;ni++){
      int r  = (wn<<6) + (ni<<4) + (l&15);
      int ch = (l>>4) ^ ((r>>1)&3);
      bv[ni] = *(const bf16x8*)(BsB + b*8192 + r*64 + ch*16);
    }
    #pragma unroll
    for (int mi=0;mi<4;mi++)
      #pragma unroll
      for (int ni=0;ni<4;ni++)
        acc[mi][ni] = __builtin_amdgcn_mfma_f32_16x16x32_bf16(av[mi], bv[ni], acc[mi][ni], 0,0,0);
  };

  stage(0, 0);
  int cur = 0;
  for (int kt=0; kt<NTK-1; ++kt){
    stage(cur^1, kt+1);
    wait_vm<4>();                 // own loads for buf[cur] done; next 4 in flight
    RAW_BARRIER();
    compute(cur);
    asm volatile("s_waitcnt lgkmcnt(0)" ::: "memory");
    RAW_BARRIER();
    cur ^= 1;
  }
  wait_vm<0>();
  RAW_BARRIER();
  compute(cur);

  int lc = l&15, lq = l>>4;
  #pragma unroll
  for (int ni=0;ni<4;ni++){
    int col = n0 + (wn<<6) + (ni<<4) + lc;
    float bcol = bias[e*DFF + col];
    #pragma unroll
    for (int mi=0;mi<4;mi++){
      int rbase = row0 + (wm<<6) + (mi<<4) + lq*4;
      #pragma unroll
      for (int q=0;q<4;q++){
        float v = acc[mi][ni][q] + bcol;
        v = v>0.f ? v : 0.f;
        outH[(size_t)(rbase+q)*DFF + col] = f2bf(v);
      }
    }
  }
}

// ---- GEMM2 split-K=2: 64x128 tile, BK=32, 4 waves 1Mx4N, 24KB LDS -> 6 blk/CU ----
// Disjoint partial stores P[kh][rows][cols] -> deterministic, no atomics.
__global__ __launch_bounds__(256,4) void gemm2s_k(
    const unsigned short* __restrict__ A,
    const unsigned short* __restrict__ Bw,
    float* __restrict__ P,               // [2][PMAX][512] fp32 partials
    const int* __restrict__ hdr)
{
  constexpr int NWG = 2*MAXT*4*2;              // 1152
  constexpr int NTK = 32;                      // K-half 1024 / 32
  __shared__ __align__(16) unsigned short As[2*64*32];    // 8KB
  __shared__ __align__(16) unsigned short Bs[2*128*32];   // 16KB

  int wg  = blockIdx.x;
  int swz = (wg & 7)*(NWG/8) + (wg >> 3);
  int m   = swz >> 3;
  int nt  = (swz >> 1) & 3;
  int kh  = swz & 1;

  if (m >= 2*hdr[HD_NTILES]) return;
  int e    = hdr[HD_TILE_E+(m>>1)];
  int row0 = hdr[HD_TILE_R+(m>>1)] + ((m&1)<<6);
  int n0   = nt << 7;

  int tid = threadIdx.x;
  int w = tid>>6, l = tid&63;

  const unsigned short* Ag = A  + (size_t)row0*DFF + (size_t)kh*1024;
  const unsigned short* Bg = Bw + (size_t)e*D_MODEL*DFF + (size_t)n0*DFF + (size_t)kh*1024;

  f32x4 acc[4][2];
  f32x4 zz = {0.f,0.f,0.f,0.f};
  #pragma unroll
  for (int i=0;i<4;i++)
    #pragma unroll
    for (int j=0;j<2;j++) acc[i][j] = zz;

  int srow = tid>>2;              // 0..63 rows per 4KB issue
  int c4   = tid&3;
  char* AsB = (char*)As;
  char* BsB = (char*)Bs;

  auto stage = [&](int b, int kt){
    {
      int r  = srow;
      int sc = (c4 ^ ((r>>1)&3))*8;
      const unsigned short* ga = Ag + (size_t)r*DFF + kt*32 + sc;
      int ldso = b*4096 + tid*16;
      __builtin_amdgcn_global_load_lds((const __attribute__((address_space(1))) void*)ga,
                                       (__attribute__((address_space(3))) void*)(AsB + ldso), 16, 0, 0);
    }
    #pragma unroll
    for (int i=0;i<2;i++){
      int r  = i*64 + srow;
      int sc = (c4 ^ ((r>>1)&3))*8;
      const unsigned short* gb = Bg + (size_t)r*DFF + kt*32 + sc;
      int ldso = b*8192 + i*4096 + tid*16;
      __builtin_amdgcn_global_load_lds((const __attribute__((address_space(1))) void*)gb,
                                       (__attribute__((address_space(3))) void*)(BsB + ldso), 16, 0, 0);
    }
  };

  auto compute = [&](int b){
    bf16x8 av[4], bv[2];
    #pragma unroll
    for (int mi=0;mi<4;mi++){
      int r  = (mi<<4) + (l&15);
      int ch = (l>>4) ^ ((r>>1)&3);
      av[mi] = *(const bf16x8*)(AsB + b*4096 + r*64 + ch*16);
    }
    #pragma unroll
    for (int ni=0;ni<2;ni++){
      int r  = (w<<5) + (ni<<4) + (l&15);
      int ch = (l>>4) ^ ((r>>1)&3);
      bv[ni] = *(const bf16x8*)(BsB + b*8192 + r*64 + ch*16);
    }
    #pragma unroll
    for (int mi=0;mi<4;mi++)
      #pragma unroll
      for (int ni=0;ni<2;ni++)
        acc[mi][ni] = __builtin_amdgcn_mfma_f32_16x16x32_bf16(av[mi], bv[ni], acc[mi][ni], 0,0,0);
  };

  stage(0, 0);
  int cur = 0;
  for (int kt=0; kt<NTK-1; ++kt){
    stage(cur^1, kt+1);
    wait_vm<3>();
    RAW_BARRIER();
    compute(cur);
    asm volatile("s_waitcnt lgkmcnt(0)" ::: "memory");
    RAW_BARRIER();
    cur ^= 1;
  }
  wait_vm<0>();
  RAW_BARRIER();
  compute(cur);

  float* Pk = P + (size_t)kh*PMAX*D_MODEL;
  int lc = l&15, lq = l>>4;
  #pragma unroll
  for (int ni=0;ni<2;ni++){
    int col = n0 + (w<<5) + (ni<<4) + lc;
    #pragma unroll
    for (int mi=0;mi<4;mi++){
      int rbase = row0 + (mi<<4) + lq*4;
      #pragma unroll
      for (int q=0;q<4;q++)
        Pk[(size_t)(rbase+q)*D_MODEL + col] = acc[mi][ni][q];
    }
  }
}

// ---- fallback GEMM2 (BK=64, atomics) for small ws: 64x128, 4 waves ----
__global__ __launch_bounds__(256,2) void gemm2f_k(
    const unsigned short* __restrict__ A,
    const unsigned short* __restrict__ Bw,
    const float* __restrict__ bias,
    float* __restrict__ outO,
    const float* __restrict__ pair_w,
    const int* __restrict__ hdr,
    const int* __restrict__ gtk)
{
  constexpr int NWG = 2*MAXT*4;
  constexpr int NTK = DFF/64;
  __shared__ __align__(16) unsigned short As[2*64*64];
  __shared__ __align__(16) unsigned short Bs[2*128*64];

  int wg  = blockIdx.x;
  int swz = (wg & 7)*(NWG/8) + (wg >> 3);
  int m   = swz >> 2;
  int n0  = (swz & 3) << 7;
  if (m >= 2*hdr[HD_NTILES]) return;
  int e    = hdr[HD_TILE_E+(m>>1)];
  int row0 = hdr[HD_TILE_R+(m>>1)] + ((m&1)<<6);

  int tid = threadIdx.x;
  int w = tid>>6, l = tid&63;
  const unsigned short* Ag = A  + (size_t)row0*DFF;
  const unsigned short* Bg = Bw + (size_t)e*D_MODEL*DFF + (size_t)n0*DFF;

  f32x4 acc[4][2];
  f32x4 zz = {0.f,0.f,0.f,0.f};
  #pragma unroll
  for (int i=0;i<4;i++)
    #pragma unroll
    for (int j=0;j<2;j++) acc[i][j] = zz;

  int srow = (w<<3) + (l>>3);
  int c8   = l&7;
  char* AsB = (char*)As;
  char* BsB = (char*)Bs;

  auto stage = [&](int b, int kt){
    #pragma unroll
    for (int i=0;i<2;i++){
      int r  = i*32 + srow;
      int sc = (c8 ^ (r&7))*8;
      const unsigned short* ga = Ag + (size_t)r*DFF + kt*64 + sc;
      int ldso = b*8192 + i*4096 + w*1024 + l*16;
      __builtin_amdgcn_global_load_lds((const __attribute__((address_space(1))) void*)ga,
                                       (__attribute__((address_space(3))) void*)(AsB + ldso), 16, 0, 0);
    }
    #pragma unroll
    for (int i=0;i<4;i++){
      int r  = i*32 + srow;
      int sc = (c8 ^ (r&7))*8;
      const unsigned short* gb = Bg + (size_t)r*DFF + kt*64 + sc;
      int ldso = b*16384 + i*4096 + w*1024 + l*16;
      __builtin_amdgcn_global_load_lds((const __attribute__((address_space(1))) void*)gb,
                                       (__attribute__((address_space(3))) void*)(BsB + ldso), 16, 0, 0);
    }
  };

  auto compute = [&](int b){
    #pragma unroll
    for (int kk=0;kk<2;kk++){
      bf16x8 av[4], bv[2];
      #pragma unroll
      for (int mi=0;mi<4;mi++){
        int r  = (mi<<4) + (l&15);
        int ch = ((kk<<2) + (l>>4)) ^ (r&7);
        av[mi] = *(const bf16x8*)(AsB + b*8192 + r*128 + ch*16);
      }
      #pragma unroll
      for (int ni=0;ni<2;ni++){
        int r  = (w<<5) + (ni<<4) + (l&15);
        int ch = ((kk<<2) + (l>>4)) ^ (r&7);
        bv[ni] = *(const bf16x8*)(BsB + b*16384 + r*128 + ch*16);
      }
      #pragma unroll
      for (int mi=0;mi<4;mi++)
        #pragma unroll
        for (int ni=0;ni<2;ni++)
          acc[mi][ni] = __builtin_amdgcn_mfma_f32_16x16x32_bf16(av[mi], bv[ni], acc[mi][ni], 0,0,0);
    }
  };

  stage(0, 0);
  int cur = 0;
  for (int kt=0; kt<NTK-1; ++kt){
    stage(cur^1, kt+1);
    wait_vm<6>();
    RAW_BARRIER();
    compute(cur);
    asm volatile("s_waitcnt lgkmcnt(0)" ::: "memory");
    RAW_BARRIER();
    cur ^= 1;
  }
  wait_vm<0>();
  RAW_BARRIER();
  compute(cur);

  int lc = l&15, lq = l>>4;
  #pragma unroll
  for (int ni=0;ni<2;ni++){
    int col = n0 + (w<<5) + (ni<<4) + lc;
    float bcol = bias[e*D_MODEL + col];
    #pragma unroll
    for (int mi=0;mi<4;mi++){
      int rbase = row0 + (mi<<4) + lq*4;
      #pragma unroll
      for (int q=0;q<4;q++){
        int gr = rbase + q;
        float v = acc[mi][ni][q] + bcol;
        int tk = gtk[gr];
        if (tk>=0){
          float wgt = pair_w[tk];
          atomicAdd(&outO[(size_t)(tk>>1)*D_MODEL + col], wgt*v);
        }
      }
    }
  }
}

// ---- combine: out[t] = w0*(P0[r0]+P1[r0]+b[e0]) + w1*(P0[r1]+P1[r1]+b[e1]) ----
__global__ void combine_kernel(const float* __restrict__ P, const int* __restrict__ pr,
                               const int* __restrict__ pair_e, const float* __restrict__ pair_w,
                               const float* __restrict__ b2, float* __restrict__ out){
  int id = blockIdx.x*256 + threadIdx.x;      // one per 4 cols
  int t = id>>7, c = (id&127)*4;
  int r0 = pr[2*t], r1 = pr[2*t+1];
  int e0 = pair_e[2*t], e1 = pair_e[2*t+1];
  float w0 = pair_w[2*t], w1 = pair_w[2*t+1];
  const float* P1 = P + (size_t)PMAX*D_MODEL;
  float4 a0 = *(const float4*)(P  + (size_t)r0*D_MODEL + c);
  float4 a1 = *(const float4*)(P1 + (size_t)r0*D_MODEL + c);
  float4 c0 = *(const float4*)(P  + (size_t)r1*D_MODEL + c);
  float4 c1 = *(const float4*)(P1 + (size_t)r1*D_MODEL + c);
  float4 bb0 = *(const float4*)(b2 + (size_t)e0*D_MODEL + c);
  float4 bb1 = *(const float4*)(b2 + (size_t)e1*D_MODEL + c);
  float4 r;
  r.x = w0*(a0.x+a1.x+bb0.x) + w1*(c0.x+c1.x+bb1.x);
  r.y = w0*(a0.y+a1.y+bb0.y) + w1*(c0.y+c1.y+bb1.y);
  r.z = w0*(a0.z+a1.z+bb0.z) + w1*(c0.z+c1.z+bb1.z);
  r.w = w0*(a0.w+a1.w+bb0.w) + w1*(c0.w+c1.w+bb1.w);
  *(float4*)(out + (size_t)t*D_MODEL + c) = r;
}

extern "C" void kernel_launch(void* const* d_in, const int* in_sizes, int n_in,
                              void* d_out, int out_size, void* d_ws, size_t ws_size,
                              hipStream_t stream){
  const float* x  = (const float*)d_in[0];
  const float* rw = (const float*)d_in[1];
  const float* w1 = (const float*)d_in[2];
  const float* b1 = (const float*)d_in[3];
  const float* w2 = (const float*)d_in[4];
  const float* b2 = (const float*)d_in[5];
  float* out = (float*)d_out;

  // ws layout (bytes):
  const size_t OFF_HDR  = 0;
  const size_t OFF_PE   = 1024;
  const size_t OFF_PW   = 66560;
  const size_t OFF_GTK  = 99328;                                   // PMAX*4 = 36864
  const size_t OFF_PR   = 143360;                                  // NPAIR*4 = 32768
  const size_t OFF_XG   = 180224;
  const size_t OFF_W1B  = OFF_XG  + (size_t)PMAX*D_MODEL*2;        // +9,437,184
  const size_t OFF_W2B  = OFF_W1B + (size_t)NEXP*DFF*D_MODEL*2;    // +16,777,216
  const size_t OFF_H    = OFF_W2B + (size_t)NEXP*DFF*D_MODEL*2;    // +16,777,216
  const size_t WS_BASE  = OFF_H   + (size_t)PMAX*DFF*2;            // 80,920,576
  const size_t OFF_P    = WS_BASE;
  const size_t WS_SPLIT = OFF_P + (size_t)2*PMAX*D_MODEL*4;        // 118,669,312
  if (ws_size < WS_BASE) return;   // refuse to scribble OOB (fails absmax cleanly)
  bool split = (ws_size >= WS_SPLIT);

  char* ws = (char*)d_ws;
  int*   hdr    = (int*)(ws + OFF_HDR);
  int*   pair_e = (int*)(ws + OFF_PE);
  float* pair_w = (float*)(ws + OFF_PW);
  int*   gtk    = (int*)(ws + OFF_GTK);
  int*   pr     = (int*)(ws + OFF_PR);
  unsigned short* xg  = (unsigned short*)(ws + OFF_XG);
  unsigned short* w1b = (unsigned short*)(ws + OFF_W1B);
  unsigned short* w2b = (unsigned short*)(ws + OFF_W2B);
  unsigned short* h   = (unsigned short*)(ws + OFF_H);
  float*          P   = (float*)(ws + OFF_P);

  hipMemsetAsync(hdr, 0, 1024, stream);
  router_top2<<<LTOK, 64, 0, stream>>>(x, rw, pair_e, pair_w);
  convw_kernel<<<8192, 256, 0, stream>>>(w1, w2, w1b, w2b);
  count_kernel<<<NPAIR/1024, 256, 0, stream>>>(pair_e, hdr);
  plan_kernel<<<1, 256, 0, stream>>>(hdr, gtk);
  assign_gather_kernel<<<NPAIR/256, 256, 0, stream>>>(pair_e, hdr, gtk, pr, x, xg);
  gemm1_k<<<MAXT*16, 256, 0, stream>>>(xg, w1b, b1, h, hdr);
  if (split){
    gemm2s_k<<<2*MAXT*4*2, 256, 0, stream>>>(h, w2b, P, hdr);
    combine_kernel<<<(LTOK*128)/256, 256, 0, stream>>>(P, pr, pair_e, pair_w, b2, out);
  } else {
    hipMemsetAsync(out, 0, (size_t)LTOK*D_MODEL*sizeof(float), stream);
    gemm2f_k<<<2*MAXT*4, 256, 0, stream>>>(h, w2b, b2, out, pair_w, hdr, gtk);
  }
}

// Round 11
// 135.223 us; speedup vs baseline: 1.0743x; 1.0743x over previous
//
#include <hip/hip_runtime.h>

#define D_MODEL 512
#define DFF 2048
#define NEXP 8
#define LTOK 4096          // B*N tokens
#define NPAIR 8192         // LTOK * K
#define PMAX 9216          // padded gathered rows (8192 + 8*128)
#define MAXT 72            // max 128-row M-tiles

// hdr (int) offsets within ws
#define HD_COUNTS 0
#define HD_CURSOR 8
#define HD_OFF    16
#define HD_NTILES 25
#define HD_TILE_E 32
#define HD_TILE_R 112

typedef __attribute__((ext_vector_type(8))) short bf16x8;
typedef __attribute__((ext_vector_type(4))) float f32x4;

__device__ __forceinline__ unsigned short f2bf(float f){
  unsigned u = __builtin_bit_cast(unsigned, f);
  u += 0x7fffu + ((u>>16)&1u);        // RNE round to bf16
  return (unsigned short)(u>>16);
}

template<int N> __device__ __forceinline__ void wait_vm(){
  if constexpr (N==6)      asm volatile("s_waitcnt vmcnt(6)" ::: "memory");
  else                     asm volatile("s_waitcnt vmcnt(0)" ::: "memory");
}
#define RAW_BARRIER() asm volatile("s_barrier" ::: "memory")

// ------- router: fp64 logits, top-2, weights; 4 tokens per 256-thr block -------
__global__ void router_top2(const float* __restrict__ x, const float* __restrict__ rw,
                            int* __restrict__ pair_e, float* __restrict__ pair_w){
  int t = blockIdx.x*4 + (threadIdx.x>>6);
  int l = threadIdx.x & 63;
  const float* xr = x + (size_t)t*D_MODEL;
  float xv[8];
  #pragma unroll
  for (int j=0;j<8;j++) xv[j] = xr[j*64+l];
  double lg[NEXP];
  #pragma unroll
  for (int e=0;e<NEXP;e++){
    const float* we = rw + e*D_MODEL;
    double s = 0.0;
    #pragma unroll
    for (int j=0;j<8;j++) s += (double)xv[j] * (double)we[j*64+l];
    #pragma unroll
    for (int off=32; off; off>>=1) s += __shfl_xor(s, off);
    lg[e] = s;
  }
  if (l==0){
    double mx = lg[0];
    #pragma unroll
    for (int e=1;e<NEXP;e++) if (lg[e]>mx) mx = lg[e];
    double p[NEXP], sum = 0.0;
    #pragma unroll
    for (int e=0;e<NEXP;e++){ p[e] = exp(lg[e]-mx); sum += p[e]; }
    #pragma unroll
    for (int e=0;e<NEXP;e++) p[e] /= sum;
    int i0 = 0;
    for (int e=1;e<NEXP;e++) if (p[e] > p[i0]) i0 = e;        // ties -> lower idx
    int i1 = (i0==0) ? 1 : 0;
    for (int e=0;e<NEXP;e++){ if (e==i0) continue; if (p[e] > p[i1]) i1 = e; }
    double s2 = p[i0] + p[i1] + 1e-9;
    pair_e[2*t]   = i0;  pair_e[2*t+1] = i1;
    pair_w[2*t]   = (float)(p[i0]/s2);
    pair_w[2*t+1] = (float)(p[i1]/s2);
  }
}

// ---------------- convert w1,w2 fp32 -> bf16 ----------------
__global__ void convw_kernel(const float* __restrict__ w1, const float* __restrict__ w2,
                             unsigned short* __restrict__ w1b, unsigned short* __restrict__ w2b){
  int id = blockIdx.x*256 + threadIdx.x;     // one per 8 elements
  const int per = NEXP*DFF*D_MODEL/8;        // 1048576
  const float* src; unsigned short* dst; int k;
  if (id < per){ src = w1; dst = w1b; k = id; }
  else         { src = w2; dst = w2b; k = id - per; }
  const float4* s = (const float4*)(src + (size_t)k*8);
  float4 a = s[0], b = s[1];
  uint4 o;
  o.x = (unsigned)f2bf(a.x) | ((unsigned)f2bf(a.y)<<16);
  o.y = (unsigned)f2bf(a.z) | ((unsigned)f2bf(a.w)<<16);
  o.z = (unsigned)f2bf(b.x) | ((unsigned)f2bf(b.y)<<16);
  o.w = (unsigned)f2bf(b.z) | ((unsigned)f2bf(b.w)<<16);
  *(uint4*)(dst + (size_t)k*8) = o;
}

// ---------------- count: LDS histogram, 8 global atomics per block ----------------
__global__ void count_kernel(const int* __restrict__ pair_e, int* __restrict__ hdr){
  __shared__ int cnt[NEXP];
  int tid = threadIdx.x;
  if (tid < NEXP) cnt[tid] = 0;
  __syncthreads();
  int base = blockIdx.x*1024;
  #pragma unroll
  for (int i=0;i<4;i++) atomicAdd(&cnt[pair_e[base + i*256 + tid]], 1);
  __syncthreads();
  if (tid < NEXP) atomicAdd(&hdr[HD_COUNTS+tid], cnt[tid]);
}

// ---------------- plan: padded offsets + tile table + gtk defaults ----------------
__global__ void plan_kernel(int* __restrict__ hdr, int* __restrict__ gtk){
  if (threadIdx.x==0){
    int off=0, nt=0;
    for (int e=0;e<NEXP;e++){
      hdr[HD_OFF+e]=off;
      int c = hdr[HD_COUNTS+e];
      int tiles = (c+127)>>7;
      for (int i=0;i<tiles;i++){ hdr[HD_TILE_E+nt]=e; hdr[HD_TILE_R+nt]=off+(i<<7); nt++; }
      off += tiles<<7;
    }
    hdr[HD_OFF+NEXP]=off;
    hdr[HD_NTILES]=nt;
  }
  for (int i=threadIdx.x; i<PMAX; i+=blockDim.x) gtk[i]=-1;
}

// -------- assign + gather: LDS rank, range reservation, then copy x rows --------
__global__ void assign_gather_kernel(const int* __restrict__ pair_e, int* __restrict__ hdr,
                                     int* __restrict__ gtk, int* __restrict__ pr,
                                     const float* __restrict__ x,
                                     unsigned short* __restrict__ xg){
  __shared__ int cnt[NEXP];
  __shared__ int base[NEXP];
  __shared__ int rowbuf[256];
  int tid = threadIdx.x;
  if (tid < NEXP) cnt[tid] = 0;
  __syncthreads();
  int id = blockIdx.x*256 + tid;
  int e = pair_e[id];
  int myrank = atomicAdd(&cnt[e], 1);           // LDS atomic
  __syncthreads();
  if (tid < NEXP) base[tid] = atomicAdd(&hdr[HD_CURSOR+tid], cnt[tid]);  // 8 global/block
  __syncthreads();
  int row = hdr[HD_OFF+e] + base[e] + myrank;
  gtk[row] = id;
  pr[id]   = row;
  rowbuf[tid] = row;
  __syncthreads();
  int grp = tid>>6, sub = tid&63;
  int base0 = blockIdx.x*256;
  for (int p = grp; p < 256; p += 4){
    int r = rowbuf[p];
    int t = (base0 + p)>>1;
    const float4* s = (const float4*)(x + (size_t)t*D_MODEL + sub*8);
    float4 a = s[0], b = s[1];
    uint4 o;
    o.x = (unsigned)f2bf(a.x) | ((unsigned)f2bf(a.y)<<16);
    o.y = (unsigned)f2bf(a.z) | ((unsigned)f2bf(a.w)<<16);
    o.z = (unsigned)f2bf(b.x) | ((unsigned)f2bf(b.y)<<16);
    o.w = (unsigned)f2bf(b.z) | ((unsigned)f2bf(b.w)<<16);
    *(uint4*)(xg + (size_t)r*D_MODEL + sub*8) = o;
  }
}

// ---- unified grouped GEMM: 64x128 tile, BK=64, 4 waves 1Mx4N, 48KB LDS, 2-phase ----
// LDK: full K row stride. KLEN: per-block K extent. NT_N: N-tiles. SPLIT: K splits.
// NDIM: B operand leading rows (DFF or D_MODEL).
// MODE 0: outH[gr*DFF+col] = relu(acc+bias) bf16
// MODE 1: P[kh][gr][col] = acc (fp32, disjoint -> deterministic)
template<int LDK, int KLEN, int NT_N, int SPLIT, int NDIM, int MODE>
__global__ __launch_bounds__(256,3) void gemmS(
    const unsigned short* __restrict__ A,
    const unsigned short* __restrict__ Bw,
    const float* __restrict__ bias,
    unsigned short* __restrict__ outH,
    float* __restrict__ P,
    const int* __restrict__ hdr)
{
  constexpr int NWG = 2*MAXT*NT_N*SPLIT;
  constexpr int NTK = KLEN/64;
  __shared__ __align__(16) unsigned short As[2*64*64];    // 16KB
  __shared__ __align__(16) unsigned short Bs[2*128*64];   // 32KB

  int wg  = blockIdx.x;
  int swz = (wg & 7)*(NWG/8) + (wg >> 3);
  int m   = swz / (NT_N*SPLIT);
  int rem = swz % (NT_N*SPLIT);
  int nt  = rem / SPLIT;
  int kh  = rem % SPLIT;

  if (m >= 2*hdr[HD_NTILES]) return;
  int e    = hdr[HD_TILE_E+(m>>1)];
  int row0 = hdr[HD_TILE_R+(m>>1)] + ((m&1)<<6);
  int n0   = nt << 7;

  int tid = threadIdx.x;
  int w = tid>>6, l = tid&63;

  const unsigned short* Ag = A  + (size_t)row0*LDK + (size_t)kh*KLEN;
  const unsigned short* Bg = Bw + (size_t)e*NDIM*LDK + (size_t)n0*LDK + (size_t)kh*KLEN;

  f32x4 acc[4][2];
  f32x4 zz = {0.f,0.f,0.f,0.f};
  #pragma unroll
  for (int i=0;i<4;i++)
    #pragma unroll
    for (int j=0;j<2;j++) acc[i][j] = zz;

  int srow = (w<<3) + (l>>3);     // 0..31 per issue
  int c8   = l&7;                 // 16B chunk within 128B row
  char* AsB = (char*)As;
  char* BsB = (char*)Bs;

  auto stage = [&](int b, int kt){
    #pragma unroll
    for (int i=0;i<2;i++){
      int r  = i*32 + srow;
      int sc = (c8 ^ (r&7))*8;                       // inverse-swizzled source (elems)
      const unsigned short* ga = Ag + (size_t)r*LDK + kt*64 + sc;
      int ldso = b*8192 + i*4096 + w*1024 + l*16;    // linear LDS dest (bytes)
      __builtin_amdgcn_global_load_lds((const __attribute__((address_space(1))) void*)ga,
                                       (__attribute__((address_space(3))) void*)(AsB + ldso), 16, 0, 0);
    }
    #pragma unroll
    for (int i=0;i<4;i++){
      int r  = i*32 + srow;
      int sc = (c8 ^ (r&7))*8;
      const unsigned short* gb = Bg + (size_t)r*LDK + kt*64 + sc;
      int ldso = b*16384 + i*4096 + w*1024 + l*16;
      __builtin_amdgcn_global_load_lds((const __attribute__((address_space(1))) void*)gb,
                                       (__attribute__((address_space(3))) void*)(BsB + ldso), 16, 0, 0);
    }
  };

  auto compute = [&](int b){
    #pragma unroll
    for (int kk=0;kk<2;kk++){
      bf16x8 av[4], bv[2];
      #pragma unroll
      for (int mi=0;mi<4;mi++){
        int r  = (mi<<4) + (l&15);
        int ch = ((kk<<2) + (l>>4)) ^ (r&7);         // swizzled read chunk
        av[mi] = *(const bf16x8*)(AsB + b*8192 + r*128 + ch*16);
      }
      #pragma unroll
      for (int ni=0;ni<2;ni++){
        int r  = (w<<5) + (ni<<4) + (l&15);
        int ch = ((kk<<2) + (l>>4)) ^ (r&7);
        bv[ni] = *(const bf16x8*)(BsB + b*16384 + r*128 + ch*16);
      }
      #pragma unroll
      for (int mi=0;mi<4;mi++)
        #pragma unroll
        for (int ni=0;ni<2;ni++)
          acc[mi][ni] = __builtin_amdgcn_mfma_f32_16x16x32_bf16(av[mi], bv[ni], acc[mi][ni], 0,0,0);
    }
  };

  stage(0, 0);
  int cur = 0;
  for (int kt=0; kt<NTK-1; ++kt){
    stage(cur^1, kt+1);
    wait_vm<6>();                 // own 6 loads for buf[cur] done; next 6 in flight
    RAW_BARRIER();
    compute(cur);
    asm volatile("s_waitcnt lgkmcnt(0)" ::: "memory");
    RAW_BARRIER();
    cur ^= 1;
  }
  wait_vm<0>();
  RAW_BARRIER();
  compute(cur);

  int lc = l&15, lq = l>>4;
  #pragma unroll
  for (int ni=0;ni<2;ni++){
    int col = n0 + (w<<5) + (ni<<4) + lc;
    float bcol = (MODE==0) ? bias[e*DFF + col] : 0.f;
    #pragma unroll
    for (int mi=0;mi<4;mi++){
      int rbase = row0 + (mi<<4) + lq*4;
      #pragma unroll
      for (int q=0;q<4;q++){
        int gr = rbase + q;
        float v = acc[mi][ni][q] + bcol;
        if (MODE==0){
          v = v>0.f ? v : 0.f;
          outH[(size_t)gr*DFF + col] = f2bf(v);
        } else {
          float* Pk = P + (size_t)kh*PMAX*D_MODEL;
          Pk[(size_t)gr*D_MODEL + col] = v;
        }
      }
    }
  }
}

// ---- fallback GEMM2 (BK=64, atomics) for small ws: 64x128, 4 waves ----
__global__ __launch_bounds__(256,2) void gemm2f_k(
    const unsigned short* __restrict__ A,
    const unsigned short* __restrict__ Bw,
    const float* __restrict__ bias,
    float* __restrict__ outO,
    const float* __restrict__ pair_w,
    const int* __restrict__ hdr,
    const int* __restrict__ gtk)
{
  constexpr int NWG = 2*MAXT*4;
  constexpr int NTK = DFF/64;
  __shared__ __align__(16) unsigned short As[2*64*64];
  __shared__ __align__(16) unsigned short Bs[2*128*64];

  int wg  = blockIdx.x;
  int swz = (wg & 7)*(NWG/8) + (wg >> 3);
  int m   = swz >> 2;
  int n0  = (swz & 3) << 7;
  if (m >= 2*hdr[HD_NTILES]) return;
  int e    = hdr[HD_TILE_E+(m>>1)];
  int row0 = hdr[HD_TILE_R+(m>>1)] + ((m&1)<<6);

  int tid = threadIdx.x;
  int w = tid>>6, l = tid&63;
  const unsigned short* Ag = A  + (size_t)row0*DFF;
  const unsigned short* Bg = Bw + (size_t)e*D_MODEL*DFF + (size_t)n0*DFF;

  f32x4 acc[4][2];
  f32x4 zz = {0.f,0.f,0.f,0.f};
  #pragma unroll
  for (int i=0;i<4;i++)
    #pragma unroll
    for (int j=0;j<2;j++) acc[i][j] = zz;

  int srow = (w<<3) + (l>>3);
  int c8   = l&7;
  char* AsB = (char*)As;
  char* BsB = (char*)Bs;

  auto stage = [&](int b, int kt){
    #pragma unroll
    for (int i=0;i<2;i++){
      int r  = i*32 + srow;
      int sc = (c8 ^ (r&7))*8;
      const unsigned short* ga = Ag + (size_t)r*DFF + kt*64 + sc;
      int ldso = b*8192 + i*4096 + w*1024 + l*16;
      __builtin_amdgcn_global_load_lds((const __attribute__((address_space(1))) void*)ga,
                                       (__attribute__((address_space(3))) void*)(AsB + ldso), 16, 0, 0);
    }
    #pragma unroll
    for (int i=0;i<4;i++){
      int r  = i*32 + srow;
      int sc = (c8 ^ (r&7))*8;
      const unsigned short* gb = Bg + (size_t)r*DFF + kt*64 + sc;
      int ldso = b*16384 + i*4096 + w*1024 + l*16;
      __builtin_amdgcn_global_load_lds((const __attribute__((address_space(1))) void*)gb,
                                       (__attribute__((address_space(3))) void*)(BsB + ldso), 16, 0, 0);
    }
  };

  auto compute = [&](int b){
    #pragma unroll
    for (int kk=0;kk<2;kk++){
      bf16x8 av[4], bv[2];
      #pragma unroll
      for (int mi=0;mi<4;mi++){
        int r  = (mi<<4) + (l&15);
        int ch = ((kk<<2) + (l>>4)) ^ (r&7);
        av[mi] = *(const bf16x8*)(AsB + b*8192 + r*128 + ch*16);
      }
      #pragma unroll
      for (int ni=0;ni<2;ni++){
        int r  = (w<<5) + (ni<<4) + (l&15);
        int ch = ((kk<<2) + (l>>4)) ^ (r&7);
        bv[ni] = *(const bf16x8*)(BsB + b*16384 + r*128 + ch*16);
      }
      #pragma unroll
      for (int mi=0;mi<4;mi++)
        #pragma unroll
        for (int ni=0;ni<2;ni++)
          acc[mi][ni] = __builtin_amdgcn_mfma_f32_16x16x32_bf16(av[mi], bv[ni], acc[mi][ni], 0,0,0);
    }
  };

  stage(0, 0);
  int cur = 0;
  for (int kt=0; kt<NTK-1; ++kt){
    stage(cur^1, kt+1);
    wait_vm<6>();
    RAW_BARRIER();
    compute(cur);
    asm volatile("s_waitcnt lgkmcnt(0)" ::: "memory");
    RAW_BARRIER();
    cur ^= 1;
  }
  wait_vm<0>();
  RAW_BARRIER();
  compute(cur);

  int lc = l&15, lq = l>>4;
  #pragma unroll
  for (int ni=0;ni<2;ni++){
    int col = n0 + (w<<5) + (ni<<4) + lc;
    float bcol = bias[e*D_MODEL + col];
    #pragma unroll
    for (int mi=0;mi<4;mi++){
      int rbase = row0 + (mi<<4) + lq*4;
      #pragma unroll
      for (int q=0;q<4;q++){
        int gr = rbase + q;
        float v = acc[mi][ni][q] + bcol;
        int tk = gtk[gr];
        if (tk>=0){
          float wgt = pair_w[tk];
          atomicAdd(&outO[(size_t)(tk>>1)*D_MODEL + col], wgt*v);
        }
      }
    }
  }
}

// ---- combine: out[t] = w0*(P0[r0]+P1[r0]+b[e0]) + w1*(P0[r1]+P1[r1]+b[e1]) ----
__global__ void combine_kernel(const float* __restrict__ P, const int* __restrict__ pr,
                               const int* __restrict__ pair_e, const float* __restrict__ pair_w,
                               const float* __restrict__ b2, float* __restrict__ out){
  int id = blockIdx.x*256 + threadIdx.x;      // one per 4 cols
  int t = id>>7, c = (id&127)*4;
  int r0 = pr[2*t], r1 = pr[2*t+1];
  int e0 = pair_e[2*t], e1 = pair_e[2*t+1];
  float w0 = pair_w[2*t], w1 = pair_w[2*t+1];
  const float* P1 = P + (size_t)PMAX*D_MODEL;
  float4 a0 = *(const float4*)(P  + (size_t)r0*D_MODEL + c);
  float4 a1 = *(const float4*)(P1 + (size_t)r0*D_MODEL + c);
  float4 c0 = *(const float4*)(P  + (size_t)r1*D_MODEL + c);
  float4 c1 = *(const float4*)(P1 + (size_t)r1*D_MODEL + c);
  float4 bb0 = *(const float4*)(b2 + (size_t)e0*D_MODEL + c);
  float4 bb1 = *(const float4*)(b2 + (size_t)e1*D_MODEL + c);
  float4 r;
  r.x = w0*(a0.x+a1.x+bb0.x) + w1*(c0.x+c1.x+bb1.x);
  r.y = w0*(a0.y+a1.y+bb0.y) + w1*(c0.y+c1.y+bb1.y);
  r.z = w0*(a0.z+a1.z+bb0.z) + w1*(c0.z+c1.z+bb1.z);
  r.w = w0*(a0.w+a1.w+bb0.w) + w1*(c0.w+c1.w+bb1.w);
  *(float4*)(out + (size_t)t*D_MODEL + c) = r;
}

extern "C" void kernel_launch(void* const* d_in, const int* in_sizes, int n_in,
                              void* d_out, int out_size, void* d_ws, size_t ws_size,
                              hipStream_t stream){
  const float* x  = (const float*)d_in[0];
  const float* rw = (const float*)d_in[1];
  const float* w1 = (const float*)d_in[2];
  const float* b1 = (const float*)d_in[3];
  const float* w2 = (const float*)d_in[4];
  const float* b2 = (const float*)d_in[5];
  float* out = (float*)d_out;

  // ws layout (bytes):
  const size_t OFF_HDR  = 0;
  const size_t OFF_PE   = 1024;
  const size_t OFF_PW   = 66560;
  const size_t OFF_GTK  = 99328;                                   // PMAX*4 = 36864
  const size_t OFF_PR   = 143360;                                  // NPAIR*4 = 32768
  const size_t OFF_XG   = 180224;
  const size_t OFF_W1B  = OFF_XG  + (size_t)PMAX*D_MODEL*2;        // +9,437,184
  const size_t OFF_W2B  = OFF_W1B + (size_t)NEXP*DFF*D_MODEL*2;    // +16,777,216
  const size_t OFF_H    = OFF_W2B + (size_t)NEXP*DFF*D_MODEL*2;    // +16,777,216
  const size_t WS_BASE  = OFF_H   + (size_t)PMAX*DFF*2;            // 80,920,576
  const size_t OFF_P    = WS_BASE;
  const size_t WS_SPLIT = OFF_P + (size_t)2*PMAX*D_MODEL*4;        // 118,669,312
  if (ws_size < WS_BASE) return;   // refuse to scribble OOB (fails absmax cleanly)
  bool split = (ws_size >= WS_SPLIT);

  char* ws = (char*)d_ws;
  int*   hdr    = (int*)(ws + OFF_HDR);
  int*   pair_e = (int*)(ws + OFF_PE);
  float* pair_w = (float*)(ws + OFF_PW);
  int*   gtk    = (int*)(ws + OFF_GTK);
  int*   pr     = (int*)(ws + OFF_PR);
  unsigned short* xg  = (unsigned short*)(ws + OFF_XG);
  unsigned short* w1b = (unsigned short*)(ws + OFF_W1B);
  unsigned short* w2b = (unsigned short*)(ws + OFF_W2B);
  unsigned short* h   = (unsigned short*)(ws + OFF_H);
  float*          P   = (float*)(ws + OFF_P);

  hipMemsetAsync(hdr, 0, 1024, stream);
  router_top2<<<LTOK/4, 256, 0, stream>>>(x, rw, pair_e, pair_w);
  convw_kernel<<<8192, 256, 0, stream>>>(w1, w2, w1b, w2b);
  count_kernel<<<NPAIR/1024, 256, 0, stream>>>(pair_e, hdr);
  plan_kernel<<<1, 256, 0, stream>>>(hdr, gtk);
  assign_gather_kernel<<<NPAIR/256, 256, 0, stream>>>(pair_e, hdr, gtk, pr, x, xg);
  // GEMM1: 64x128 tiles, K=512, 16 N-tiles, grid 2304
  gemmS<D_MODEL, D_MODEL, 16, 1, DFF, 0><<<2*MAXT*16, 256, 0, stream>>>(xg, w1b, b1, h, nullptr, hdr);
  if (split){
    // GEMM2: 64x128 tiles, split-K=2 (KLEN=1024), 4 N-tiles, grid 1152
    gemmS<DFF, 1024, 4, 2, D_MODEL, 1><<<2*MAXT*4*2, 256, 0, stream>>>(h, w2b, nullptr, nullptr, P, hdr);
    combine_kernel<<<(LTOK*128)/256, 256, 0, stream>>>(P, pr, pair_e, pair_w, b2, out);
  } else {
    hipMemsetAsync(out, 0, (size_t)LTOK*D_MODEL*sizeof(float), stream);
    gemm2f_k<<<2*MAXT*4, 256, 0, stream>>>(h, w2b, b2, out, pair_w, hdr, gtk);
  }
}

// Round 12
// 128.358 us; speedup vs baseline: 1.1317x; 1.0535x over previous
//
#include <hip/hip_runtime.h>

#define D_MODEL 512
#define DFF 2048
#define NEXP 8
#define LTOK 4096          // B*N tokens
#define NPAIR 8192         // LTOK * K
#define PMAX 9216          // padded gathered rows (8192 + 8*128)
#define MAXT 72            // max 128-row M-tiles

// hdr (int) offsets within ws
#define HD_COUNTS 0
#define HD_CURSOR 8
#define HD_OFF    16
#define HD_NTILES 25
#define HD_DONE   26
#define HD_TILE_E 32
#define HD_TILE_R 112

typedef __attribute__((ext_vector_type(8))) short bf16x8;
typedef __attribute__((ext_vector_type(4))) float f32x4;

__device__ __forceinline__ unsigned short f2bf(float f){
  unsigned u = __builtin_bit_cast(unsigned, f);
  u += 0x7fffu + ((u>>16)&1u);        // RNE round to bf16
  return (unsigned short)(u>>16);
}

template<int N> __device__ __forceinline__ void wait_vm(){
  if constexpr (N==8)      asm volatile("s_waitcnt vmcnt(8)" ::: "memory");
  else if constexpr (N==6) asm volatile("s_waitcnt vmcnt(6)" ::: "memory");
  else                     asm volatile("s_waitcnt vmcnt(0)" ::: "memory");
}
#define RAW_BARRIER() asm volatile("s_barrier" ::: "memory")

// ------- router: fp64 logits, top-2, weights; 4 tokens/block; block 0 zeroes hdr -------
__global__ void router_top2(const float* __restrict__ x, const float* __restrict__ rw,
                            int* __restrict__ pair_e, float* __restrict__ pair_w,
                            int* __restrict__ hdr){
  if (blockIdx.x==0) hdr[threadIdx.x] = 0;      // 256 ints = 1KB header
  int t = blockIdx.x*4 + (threadIdx.x>>6);
  int l = threadIdx.x & 63;
  const float* xr = x + (size_t)t*D_MODEL;
  float xv[8];
  #pragma unroll
  for (int j=0;j<8;j++) xv[j] = xr[j*64+l];
  double lg[NEXP];
  #pragma unroll
  for (int e=0;e<NEXP;e++){
    const float* we = rw + e*D_MODEL;
    double s = 0.0;
    #pragma unroll
    for (int j=0;j<8;j++) s += (double)xv[j] * (double)we[j*64+l];
    #pragma unroll
    for (int off=32; off; off>>=1) s += __shfl_xor(s, off);
    lg[e] = s;
  }
  if (l==0){
    double mx = lg[0];
    #pragma unroll
    for (int e=1;e<NEXP;e++) if (lg[e]>mx) mx = lg[e];
    double p[NEXP], sum = 0.0;
    #pragma unroll
    for (int e=0;e<NEXP;e++){ p[e] = exp(lg[e]-mx); sum += p[e]; }
    #pragma unroll
    for (int e=0;e<NEXP;e++) p[e] /= sum;
    int i0 = 0;
    for (int e=1;e<NEXP;e++) if (p[e] > p[i0]) i0 = e;        // ties -> lower idx
    int i1 = (i0==0) ? 1 : 0;
    for (int e=0;e<NEXP;e++){ if (e==i0) continue; if (p[e] > p[i1]) i1 = e; }
    double s2 = p[i0] + p[i1] + 1e-9;
    pair_e[2*t]   = i0;  pair_e[2*t+1] = i1;
    pair_w[2*t]   = (float)(p[i0]/s2);
    pair_w[2*t+1] = (float)(p[i1]/s2);
  }
}

// ---------------- convert w1,w2 fp32 -> bf16 ----------------
__global__ void convw_kernel(const float* __restrict__ w1, const float* __restrict__ w2,
                             unsigned short* __restrict__ w1b, unsigned short* __restrict__ w2b){
  int id = blockIdx.x*256 + threadIdx.x;     // one per 8 elements
  const int per = NEXP*DFF*D_MODEL/8;        // 1048576
  const float* src; unsigned short* dst; int k;
  if (id < per){ src = w1; dst = w1b; k = id; }
  else         { src = w2; dst = w2b; k = id - per; }
  const float4* s = (const float4*)(src + (size_t)k*8);
  float4 a = s[0], b = s[1];
  uint4 o;
  o.x = (unsigned)f2bf(a.x) | ((unsigned)f2bf(a.y)<<16);
  o.y = (unsigned)f2bf(a.z) | ((unsigned)f2bf(a.w)<<16);
  o.z = (unsigned)f2bf(b.x) | ((unsigned)f2bf(b.y)<<16);
  o.w = (unsigned)f2bf(b.z) | ((unsigned)f2bf(b.w)<<16);
  *(uint4*)(dst + (size_t)k*8) = o;
}

// ---- count+plan fused: 8 blocks histogram; last-done block computes plan ----
__global__ void countplan_kernel(const int* __restrict__ pair_e, int* __restrict__ hdr,
                                 int* __restrict__ gtk){
  __shared__ int cnt[NEXP];
  int tid = threadIdx.x;
  if (tid < NEXP) cnt[tid] = 0;
  __syncthreads();
  int base = blockIdx.x*1024;
  #pragma unroll
  for (int i=0;i<4;i++) atomicAdd(&cnt[pair_e[base + i*256 + tid]], 1);
  __syncthreads();
  if (tid < NEXP){
    int old = atomicAdd(&hdr[HD_COUNTS+tid], cnt[tid]);   // returning form: completes
    (void)old;
  }
  for (int i = blockIdx.x*256 + tid; i < PMAX; i += 8*256) gtk[i] = -1;
  __syncthreads();
  if (tid==0){
    int done = atomicAdd(&hdr[HD_DONE], 1);
    if (done == 7){                       // last block: all counts landed
      int off=0, nt=0;
      for (int e=0;e<NEXP;e++){
        hdr[HD_OFF+e] = off;
        int c = atomicAdd(&hdr[HD_COUNTS+e], 0);          // acquire-ish read
        int tiles = (c+127)>>7;
        for (int i=0;i<tiles;i++){ hdr[HD_TILE_E+nt]=e; hdr[HD_TILE_R+nt]=off+(i<<7); nt++; }
        off += tiles<<7;
      }
      hdr[HD_OFF+NEXP]=off;
      hdr[HD_NTILES]=nt;
    }
  }
}

// -------- assign + gather: LDS rank, range reservation, then copy x rows --------
__global__ void assign_gather_kernel(const int* __restrict__ pair_e, int* __restrict__ hdr,
                                     int* __restrict__ gtk, int* __restrict__ pr,
                                     const float* __restrict__ x,
                                     unsigned short* __restrict__ xg){
  __shared__ int cnt[NEXP];
  __shared__ int base[NEXP];
  __shared__ int rowbuf[256];
  int tid = threadIdx.x;
  if (tid < NEXP) cnt[tid] = 0;
  __syncthreads();
  int id = blockIdx.x*256 + tid;
  int e = pair_e[id];
  int myrank = atomicAdd(&cnt[e], 1);           // LDS atomic
  __syncthreads();
  if (tid < NEXP) base[tid] = atomicAdd(&hdr[HD_CURSOR+tid], cnt[tid]);  // 8 global/block
  __syncthreads();
  int row = hdr[HD_OFF+e] + base[e] + myrank;
  gtk[row] = id;
  pr[id]   = row;
  rowbuf[tid] = row;
  __syncthreads();
  int grp = tid>>6, sub = tid&63;
  int base0 = blockIdx.x*256;
  for (int p = grp; p < 256; p += 4){
    int r = rowbuf[p];
    int t = (base0 + p)>>1;
    const float4* s = (const float4*)(x + (size_t)t*D_MODEL + sub*8);
    float4 a = s[0], b = s[1];
    uint4 o;
    o.x = (unsigned)f2bf(a.x) | ((unsigned)f2bf(a.y)<<16);
    o.y = (unsigned)f2bf(a.z) | ((unsigned)f2bf(a.w)<<16);
    o.z = (unsigned)f2bf(b.x) | ((unsigned)f2bf(b.y)<<16);
    o.w = (unsigned)f2bf(b.z) | ((unsigned)f2bf(b.w)<<16);
    *(uint4*)(xg + (size_t)r*D_MODEL + sub*8) = o;
  }
}

// ---------------- grouped GEMM, 2-phase double-buffered pipeline (r9-proven) -------
// MT x 128 tile, BK=64, 4 waves. MT=128: 2x2 waves of 64x64. MT=64: 1x4 waves of 64x32.
// MODE 0: outH = relu(acc+bias) bf16    MODE 1: atomicAdd(out, pair_w*(acc+bias))
template<int MT, int NDIM, int KDIM, int MODE>
__global__ __launch_bounds__(256,2) void gemm2p(
    const unsigned short* __restrict__ A,
    const unsigned short* __restrict__ Bw,
    const float* __restrict__ bias,
    unsigned short* __restrict__ outH,
    float* __restrict__ outO,
    const float* __restrict__ pair_w,
    const int* __restrict__ hdr,
    const int* __restrict__ gtk)
{
  constexpr int NT_N = NDIM/128;
  constexpr int MAXM = (MT==128) ? MAXT : 2*MAXT;
  constexpr int NWG  = MAXM*NT_N;
  constexpr int WC   = (MT==128) ? 64 : 32;
  constexpr int FN   = WC/16;
  constexpr int LPT  = MT/32 + 4;
  constexpr int ABYT = MT*128;
  constexpr int NTK  = KDIM/64;

  __shared__ __align__(16) unsigned short As[2*MT*64];
  __shared__ __align__(16) unsigned short Bs[2*128*64];

  int wg  = blockIdx.x;
  int swz = (wg & 7)*(NWG/8) + (wg >> 3);
  int m   = swz / NT_N;
  int n0  = (swz % NT_N) << 7;

  int ntiles = hdr[HD_NTILES];
  int e, row0;
  if constexpr (MT==128){
    if (m >= ntiles) return;
    e = hdr[HD_TILE_E+m];  row0 = hdr[HD_TILE_R+m];
  } else {
    if (m >= 2*ntiles) return;
    e = hdr[HD_TILE_E+(m>>1)];  row0 = hdr[HD_TILE_R+(m>>1)] + ((m&1)<<6);
  }

  int tid = threadIdx.x;
  int w = tid>>6, l = tid&63;
  int wm = (MT==128) ? (w>>1) : 0;
  int wn = (MT==128) ? (w&1)  : w;

  const unsigned short* Ag = A  + (size_t)row0*KDIM;
  const unsigned short* Bg = Bw + (size_t)e*NDIM*KDIM + (size_t)n0*KDIM;

  f32x4 acc[4][FN];
  f32x4 zz = {0.f,0.f,0.f,0.f};
  #pragma unroll
  for (int i=0;i<4;i++)
    #pragma unroll
    for (int j=0;j<FN;j++) acc[i][j] = zz;

  int srow = (w<<3) + (l>>3);
  int c8   = l&7;
  char* AsB = (char*)As;
  char* BsB = (char*)Bs;

  auto stage = [&](int b, int kt){
    #pragma unroll
    for (int i=0;i<MT/32;i++){
      int r  = i*32 + srow;
      int sc = (c8 ^ (r&7))*8;
      const unsigned short* ga = Ag + (size_t)r*KDIM + kt*64 + sc;
      int ldso = b*ABYT + i*4096 + w*1024 + l*16;
      __builtin_amdgcn_global_load_lds((const __attribute__((address_space(1))) void*)ga,
                                       (__attribute__((address_space(3))) void*)(AsB + ldso), 16, 0, 0);
    }
    #pragma unroll
    for (int i=0;i<4;i++){
      int r  = i*32 + srow;
      int sc = (c8 ^ (r&7))*8;
      const unsigned short* gb = Bg + (size_t)r*KDIM + kt*64 + sc;
      int ldso = b*16384 + i*4096 + w*1024 + l*16;
      __builtin_amdgcn_global_load_lds((const __attribute__((address_space(1))) void*)gb,
                                       (__attribute__((address_space(3))) void*)(BsB + ldso), 16, 0, 0);
    }
  };

  auto compute = [&](int b){
    #pragma unroll
    for (int kk=0;kk<2;kk++){
      bf16x8 av[4], bv[FN];
      #pragma unroll
      for (int mi=0;mi<4;mi++){
        int r  = (wm<<6) + (mi<<4) + (l&15);
        int ch = ((kk<<2) + (l>>4)) ^ (r&7);
        av[mi] = *(const bf16x8*)(AsB + b*ABYT + r*128 + ch*16);
      }
      #pragma unroll
      for (int ni=0;ni<FN;ni++){
        int r  = wn*WC + (ni<<4) + (l&15);
        int ch = ((kk<<2) + (l>>4)) ^ (r&7);
        bv[ni] = *(const bf16x8*)(BsB + b*16384 + r*128 + ch*16);
      }
      #pragma unroll
      for (int mi=0;mi<4;mi++)
        #pragma unroll
        for (int ni=0;ni<FN;ni++)
          acc[mi][ni] = __builtin_amdgcn_mfma_f32_16x16x32_bf16(av[mi], bv[ni], acc[mi][ni], 0,0,0);
    }
  };

  stage(0, 0);
  int cur = 0;
  for (int kt=0; kt<NTK-1; ++kt){
    stage(cur^1, kt+1);
    wait_vm<LPT>();
    RAW_BARRIER();
    compute(cur);
    asm volatile("s_waitcnt lgkmcnt(0)" ::: "memory");
    RAW_BARRIER();
    cur ^= 1;
  }
  wait_vm<0>();
  RAW_BARRIER();
  compute(cur);

  int lc = l&15, lq = l>>4;
  #pragma unroll
  for (int ni=0;ni<FN;ni++){
    int col = n0 + wn*WC + (ni<<4) + lc;
    float bcol = bias[e*NDIM + col];
    #pragma unroll
    for (int mi=0;mi<4;mi++){
      int rbase = row0 + (wm<<6) + (mi<<4) + lq*4;
      #pragma unroll
      for (int q=0;q<4;q++){
        int gr = rbase + q;
        float v = acc[mi][ni][q] + bcol;
        if (MODE==0){
          v = v>0.f ? v : 0.f;
          outH[(size_t)gr*NDIM + col] = f2bf(v);
        } else {
          int tk = gtk[gr];
          if (tk>=0){
            float wgt = pair_w[tk];
            atomicAdd(&outO[(size_t)(tk>>1)*D_MODEL + col], wgt*v);
          }
        }
      }
    }
  }
}

// ---- GEMM2 split-K=2, NO atomics: 64x128 tile, 4 waves, BK=64, 48KB, 3 blk/CU ----
__global__ __launch_bounds__(256,3) void gemm2s_k(
    const unsigned short* __restrict__ A,
    const unsigned short* __restrict__ Bw,
    float* __restrict__ P,               // [2][PMAX][512] fp32 partials
    const int* __restrict__ hdr)
{
  constexpr int NWG = 2*MAXT*4*2;              // 1152
  constexpr int NTK = 16;                      // K-half 1024 / 64
  __shared__ __align__(16) unsigned short As[2*64*64];    // 16KB
  __shared__ __align__(16) unsigned short Bs[2*128*64];   // 32KB

  int wg  = blockIdx.x;
  int swz = (wg & 7)*(NWG/8) + (wg >> 3);
  int m   = swz >> 3;
  int nt  = (swz >> 1) & 3;
  int kh  = swz & 1;

  if (m >= 2*hdr[HD_NTILES]) return;
  int e    = hdr[HD_TILE_E+(m>>1)];
  int row0 = hdr[HD_TILE_R+(m>>1)] + ((m&1)<<6);
  int n0   = nt << 7;

  int tid = threadIdx.x;
  int w = tid>>6, l = tid&63;

  const unsigned short* Ag = A  + (size_t)row0*DFF + (size_t)kh*1024;
  const unsigned short* Bg = Bw + (size_t)e*D_MODEL*DFF + (size_t)n0*DFF + (size_t)kh*1024;

  f32x4 acc[4][2];
  f32x4 zz = {0.f,0.f,0.f,0.f};
  #pragma unroll
  for (int i=0;i<4;i++)
    #pragma unroll
    for (int j=0;j<2;j++) acc[i][j] = zz;

  int srow = (w<<3) + (l>>3);
  int c8   = l&7;
  char* AsB = (char*)As;
  char* BsB = (char*)Bs;

  auto stage = [&](int b, int kt){
    #pragma unroll
    for (int i=0;i<2;i++){
      int r  = i*32 + srow;
      int sc = (c8 ^ (r&7))*8;
      const unsigned short* ga = Ag + (size_t)r*DFF + kt*64 + sc;
      int ldso = b*8192 + i*4096 + w*1024 + l*16;
      __builtin_amdgcn_global_load_lds((const __attribute__((address_space(1))) void*)ga,
                                       (__attribute__((address_space(3))) void*)(AsB + ldso), 16, 0, 0);
    }
    #pragma unroll
    for (int i=0;i<4;i++){
      int r  = i*32 + srow;
      int sc = (c8 ^ (r&7))*8;
      const unsigned short* gb = Bg + (size_t)r*DFF + kt*64 + sc;
      int ldso = b*16384 + i*4096 + w*1024 + l*16;
      __builtin_amdgcn_global_load_lds((const __attribute__((address_space(1))) void*)gb,
                                       (__attribute__((address_space(3))) void*)(BsB + ldso), 16, 0, 0);
    }
  };

  auto compute = [&](int b){
    #pragma unroll
    for (int kk=0;kk<2;kk++){
      bf16x8 av[4], bv[2];
      #pragma unroll
      for (int mi=0;mi<4;mi++){
        int r  = (mi<<4) + (l&15);
        int ch = ((kk<<2) + (l>>4)) ^ (r&7);
        av[mi] = *(const bf16x8*)(AsB + b*8192 + r*128 + ch*16);
      }
      #pragma unroll
      for (int ni=0;ni<2;ni++){
        int r  = (w<<5) + (ni<<4) + (l&15);
        int ch = ((kk<<2) + (l>>4)) ^ (r&7);
        bv[ni] = *(const bf16x8*)(BsB + b*16384 + r*128 + ch*16);
      }
      #pragma unroll
      for (int mi=0;mi<4;mi++)
        #pragma unroll
        for (int ni=0;ni<2;ni++)
          acc[mi][ni] = __builtin_amdgcn_mfma_f32_16x16x32_bf16(av[mi], bv[ni], acc[mi][ni], 0,0,0);
    }
  };

  stage(0, 0);
  int cur = 0;
  for (int kt=0; kt<NTK-1; ++kt){
    stage(cur^1, kt+1);
    wait_vm<6>();
    RAW_BARRIER();
    compute(cur);
    asm volatile("s_waitcnt lgkmcnt(0)" ::: "memory");
    RAW_BARRIER();
    cur ^= 1;
  }
  wait_vm<0>();
  RAW_BARRIER();
  compute(cur);

  float* Pk = P + (size_t)kh*PMAX*D_MODEL;
  int lc = l&15, lq = l>>4;
  #pragma unroll
  for (int ni=0;ni<2;ni++){
    int col = n0 + (w<<5) + (ni<<4) + lc;
    #pragma unroll
    for (int mi=0;mi<4;mi++){
      int rbase = row0 + (mi<<4) + lq*4;
      #pragma unroll
      for (int q=0;q<4;q++)
        Pk[(size_t)(rbase+q)*D_MODEL + col] = acc[mi][ni][q];
    }
  }
}

// ---- combine: out[t] = w0*(P0[r0]+P1[r0]+b[e0]) + w1*(P0[r1]+P1[r1]+b[e1]) ----
__global__ void combine_kernel(const float* __restrict__ P, const int* __restrict__ pr,
                               const int* __restrict__ pair_e, const float* __restrict__ pair_w,
                               const float* __restrict__ b2, float* __restrict__ out){
  int id = blockIdx.x*256 + threadIdx.x;      // one per 4 cols
  int t = id>>7, c = (id&127)*4;
  int r0 = pr[2*t], r1 = pr[2*t+1];
  int e0 = pair_e[2*t], e1 = pair_e[2*t+1];
  float w0 = pair_w[2*t], w1 = pair_w[2*t+1];
  const float* P1 = P + (size_t)PMAX*D_MODEL;
  float4 a0 = *(const float4*)(P  + (size_t)r0*D_MODEL + c);
  float4 a1 = *(const float4*)(P1 + (size_t)r0*D_MODEL + c);
  float4 c0 = *(const float4*)(P  + (size_t)r1*D_MODEL + c);
  float4 c1 = *(const float4*)(P1 + (size_t)r1*D_MODEL + c);
  float4 bb0 = *(const float4*)(b2 + (size_t)e0*D_MODEL + c);
  float4 bb1 = *(const float4*)(b2 + (size_t)e1*D_MODEL + c);
  float4 r;
  r.x = w0*(a0.x+a1.x+bb0.x) + w1*(c0.x+c1.x+bb1.x);
  r.y = w0*(a0.y+a1.y+bb0.y) + w1*(c0.y+c1.y+bb1.y);
  r.z = w0*(a0.z+a1.z+bb0.z) + w1*(c0.z+c1.z+bb1.z);
  r.w = w0*(a0.w+a1.w+bb0.w) + w1*(c0.w+c1.w+bb1.w);
  *(float4*)(out + (size_t)t*D_MODEL + c) = r;
}

extern "C" void kernel_launch(void* const* d_in, const int* in_sizes, int n_in,
                              void* d_out, int out_size, void* d_ws, size_t ws_size,
                              hipStream_t stream){
  const float* x  = (const float*)d_in[0];
  const float* rw = (const float*)d_in[1];
  const float* w1 = (const float*)d_in[2];
  const float* b1 = (const float*)d_in[3];
  const float* w2 = (const float*)d_in[4];
  const float* b2 = (const float*)d_in[5];
  float* out = (float*)d_out;

  // ws layout (bytes):
  const size_t OFF_HDR  = 0;
  const size_t OFF_PE   = 1024;
  const size_t OFF_PW   = 66560;
  const size_t OFF_GTK  = 99328;                                   // PMAX*4 = 36864
  const size_t OFF_PR   = 143360;                                  // NPAIR*4 = 32768
  const size_t OFF_XG   = 180224;
  const size_t OFF_W1B  = OFF_XG  + (size_t)PMAX*D_MODEL*2;        // +9,437,184
  const size_t OFF_W2B  = OFF_W1B + (size_t)NEXP*DFF*D_MODEL*2;    // +16,777,216
  const size_t OFF_H    = OFF_W2B + (size_t)NEXP*DFF*D_MODEL*2;    // +16,777,216
  const size_t WS_BASE  = OFF_H   + (size_t)PMAX*DFF*2;            // 80,920,576
  const size_t OFF_P    = WS_BASE;
  const size_t WS_SPLIT = OFF_P + (size_t)2*PMAX*D_MODEL*4;        // 118,669,312
  if (ws_size < WS_BASE) return;   // refuse to scribble OOB (fails absmax cleanly)
  bool split = (ws_size >= WS_SPLIT);

  char* ws = (char*)d_ws;
  int*   hdr    = (int*)(ws + OFF_HDR);
  int*   pair_e = (int*)(ws + OFF_PE);
  float* pair_w = (float*)(ws + OFF_PW);
  int*   gtk    = (int*)(ws + OFF_GTK);
  int*   pr     = (int*)(ws + OFF_PR);
  unsigned short* xg  = (unsigned short*)(ws + OFF_XG);
  unsigned short* w1b = (unsigned short*)(ws + OFF_W1B);
  unsigned short* w2b = (unsigned short*)(ws + OFF_W2B);
  unsigned short* h   = (unsigned short*)(ws + OFF_H);
  float*          P   = (float*)(ws + OFF_P);

  router_top2<<<LTOK/4, 256, 0, stream>>>(x, rw, pair_e, pair_w, hdr);
  convw_kernel<<<8192, 256, 0, stream>>>(w1, w2, w1b, w2b);
  countplan_kernel<<<NPAIR/1024, 256, 0, stream>>>(pair_e, hdr, gtk);
  assign_gather_kernel<<<NPAIR/256, 256, 0, stream>>>(pair_e, hdr, gtk, pr, x, xg);
  gemm2p<128, DFF, D_MODEL, 0><<<MAXT*16, 256, 0, stream>>>(xg, w1b, b1, h, nullptr, nullptr, hdr, gtk);
  if (split){
    gemm2s_k<<<2*MAXT*4*2, 256, 0, stream>>>(h, w2b, P, hdr);
    combine_kernel<<<(LTOK*128)/256, 256, 0, stream>>>(P, pr, pair_e, pair_w, b2, out);
  } else {
    hipMemsetAsync(out, 0, (size_t)LTOK*D_MODEL*sizeof(float), stream);
    gemm2p<64, D_MODEL, DFF, 1><<<2*MAXT*4, 256, 0, stream>>>(h, w2b, b2, nullptr, out, pair_w, hdr, gtk);
  }
}